// Round 1
// baseline (700.533 us; speedup 1.0000x reference)
//
#include <hip/hip_runtime.h>
#include <hip/hip_fp16.h>

typedef _Float16 h2v __attribute__((ext_vector_type(2)));
typedef unsigned int u32;
typedef unsigned short u16;

#define NB 256
#define NP 512
#define NH 256
#define NCOL 768

// ws layout in dwords (all fp16-pair packed weights)
#define OFF_WH 0
#define LEN_WH 98304            // 8 waves * 192 regs * 64 lanes
#define OFF_WI (OFF_WH + LEN_WH)      // 98304
#define LEN_WI 6912             // 9 k-pairs * 768 cols
#define OFF_W1 (OFF_WI + LEN_WI)      // 105216
#define LEN_W1 68096            // 2 * 133 * 256
#define OFF_W2 (OFF_W1 + LEN_W1)      // 173312
#define LEN_W2 65536            // 2 * 128 * 256
#define OFF_W3 (OFF_W2 + LEN_W2)      // 238848
#define LEN_W3 256              // 2 * 128
#define WS_DWORDS (OFF_W3 + LEN_W3)   // 239104 dwords = 956416 B

__device__ __forceinline__ u32 pack2(float lo, float hi) {
    h2v v; v.x = (_Float16)lo; v.y = (_Float16)hi;
    return __builtin_bit_cast(u32, v);
}

__device__ __forceinline__ float fdot2(u32 a, u32 b, float c) {
#if __has_builtin(__builtin_amdgcn_fdot2)
    return __builtin_amdgcn_fdot2(__builtin_bit_cast(h2v, a),
                                  __builtin_bit_cast(h2v, b), c, false);
#else
    h2v x = __builtin_bit_cast(h2v, a), y = __builtin_bit_cast(h2v, b);
    return c + (float)x.x * (float)y.x + (float)x.y * (float)y.y;
#endif
}

// ---------------- pack kernel: fp32 weights -> fp16-pair layouts in ws ----
__global__ __launch_bounds__(256) void pack_kernel(
    const float* __restrict__ Wi, const float* __restrict__ Whrz,
    const float* __restrict__ Whn, const float* __restrict__ W1,
    const float* __restrict__ W2, const float* __restrict__ W3,
    u32* __restrict__ ws)
{
    for (int F = blockIdx.x * 256 + threadIdx.x; F < WS_DWORDS; F += gridDim.x * 256) {
        u32 val;
        if (F < OFF_WI) {
            // Wh pack: flat = ((wid*192 + i)*64 + lane), i = c*32 + kk
            int l = F & 63; int t = F >> 6;
            int i = t % 192; int wid = t / 192;
            int c = i >> 5, kk = i & 31;
            int kw = wid & 3, cg = wid >> 2;
            int k = 64 * kw + 2 * kk;
            int col = 384 * cg + 64 * c + l;
            float lo, hi;
            if (col < 512) { lo = Whrz[k * 512 + col]; hi = Whrz[(k + 1) * 512 + col]; }
            else { lo = Whn[k * 256 + (col - 512)]; hi = Whn[(k + 1) * 256 + (col - 512)]; }
            val = pack2(lo, hi);
        } else if (F < OFF_W1) {
            int j = F - OFF_WI; int kk = j / NCOL; int col = j % NCOL;
            int k = 2 * kk;
            float lo = Wi[k * NCOL + col];
            float hi = (k + 1 < 17) ? Wi[(k + 1) * NCOL + col] : 0.f;
            val = pack2(lo, hi);
        } else if (F < OFF_W2) {
            int j = F - OFF_W1; int c = j / (133 * 256); int r = j % (133 * 256);
            int kk = r >> 8; int o = r & 255;
            int k = 2 * kk;
            float lo = W1[(c * 265 + k) * 256 + o];
            float hi = (k + 1 < 265) ? W1[(c * 265 + k + 1) * 256 + o] : 0.f;
            val = pack2(lo, hi);
        } else if (F < OFF_W3) {
            int j = F - OFF_W2; int c = j >> 15; int r = j & 32767;
            int kk = r >> 8; int o = r & 255;
            float lo = W2[(c * 256 + 2 * kk) * 256 + o];
            float hi = W2[(c * 256 + 2 * kk + 1) * 256 + o];
            val = pack2(lo, hi);
        } else {
            int j = F - OFF_W3; int c = j >> 7; int jj = j & 127;
            float lo = W3[c * 256 + 2 * jj];
            float hi = W3[c * 256 + 2 * jj + 1];
            val = pack2(lo, hi);
        }
        ws[F] = val;
    }
}

// ---------------- main kernel: one batch row per workgroup --------------
__global__ __launch_bounds__(512, 2) void qnet_kernel(
    const float* __restrict__ particles, const float* __restrict__ pweights,
    const float* __restrict__ actions, const float* __restrict__ timev,
    const float* __restrict__ bi, const float* __restrict__ bn,
    const float* __restrict__ b1, const float* __restrict__ b2,
    const float* __restrict__ b3, const int* __restrict__ nts,
    const u32* __restrict__ ws, float* __restrict__ out)
{
    __shared__ __align__(16) u32 sWi[LEN_WI];        // 27648 B, Wi fp16 pairs [9][768]
    __shared__ __align__(16) u32 sX[NP * 9];         // 18432 B, x fp16 pairs per step
    __shared__ __align__(16) float sPart[4 * NCOL];  // 12288 B, K-slice partials
    __shared__ __align__(16) u32 sH2[NH / 2];        // 512 B, h as fp16 pairs
    __shared__ __align__(16) float sHf[NH];          // 1024 B, final enc (fp32)
    __shared__ __align__(16) float sMisc[16];        // actions + norm_time

    // MLP-phase overlays (scan arrays dead by then; barriers separate uses)
    u32* sHid = sWi;            // 133 dwords: hidden fp16 pairs
    u16* sL1 = (u16*)sX;        // 512 halves
    u16* sL2 = (u16*)sPart;     // 512 halves

    const int b = blockIdx.x;
    const int tid = threadIdx.x;
    const int lane = tid & 63;
    const int wid = tid >> 6;   // 0..7
    const int kw = wid & 3;     // K-slice of 64
    const int cg = wid >> 2;    // column half (384 cols)

    // ---- load this wave's Wh fragment into registers (192 fp16 pairs) ----
    u32 wreg[192];
    {
        const u32* gp = ws + OFF_WH + (wid * 192) * 64 + lane;
        #pragma unroll
        for (int i = 0; i < 192; ++i) wreg[i] = gp[i * 64];
    }
    // ---- stage Wi pairs into LDS ----
    for (int j = tid; j < LEN_WI; j += 512) sWi[j] = ws[OFF_WI + j];
    // ---- stage this row's x sequence as fp16 pairs ----
    {
        const float4* pr = (const float4*)(particles + (long)b * NP * 16);
        for (int j = tid; j < NP * 4; j += 512) {
            float4 v = pr[j];
            int p = j >> 2, d4 = j & 3;
            sX[p * 9 + d4 * 2]     = pack2(v.x, v.y);
            sX[p * 9 + d4 * 2 + 1] = pack2(v.z, v.w);
        }
        const float* wr = pweights + (long)b * NP;
        for (int p = tid; p < NP; p += 512) sX[p * 9 + 8] = pack2(wr[p], 0.f);
    }
    if (tid < NH / 2) sH2[tid] = 0u;
    if (tid < 8) sMisc[tid] = actions[b * 8 + tid];
    if (tid == 8) sMisc[8] = timev[b] / (float)nts[0];

    float hreg = 0.f, bir = 0.f, biz = 0.f, binn = 0.f, bnn = 0.f;
    if (tid < NH) {
        bir = bi[tid]; biz = bi[NH + tid]; binn = bi[2 * NH + tid]; bnn = bn[tid];
    }
    __syncthreads();

    const int colbase = cg * 384 + lane;
    #pragma unroll 1
    for (int p = 0; p < NP; ++p) {
        // ---- main dot: this wave's K-slice x 6 columns per lane ----
        float acc[6] = {0.f, 0.f, 0.f, 0.f, 0.f, 0.f};
        const uint4* h4 = ((const uint4*)sH2) + kw * 8;
        #pragma unroll
        for (int q = 0; q < 8; ++q) {
            uint4 hv = h4[q];
            u32 hp[4] = {hv.x, hv.y, hv.z, hv.w};
            #pragma unroll
            for (int j = 0; j < 4; ++j) {
                #pragma unroll
                for (int c = 0; c < 6; ++c)
                    acc[c] = fdot2(wreg[c * 32 + q * 4 + j], hp[j], acc[c]);
            }
        }
        #pragma unroll
        for (int c = 0; c < 6; ++c)
            sPart[kw * NCOL + colbase + 64 * c] = acc[c];

        // ---- x@Wi part (independent of h): tail threads, before barrier ----
        float xr = 0.f, xz = 0.f, xn = 0.f;
        if (tid < NH) {
            xr = bir; xz = biz; xn = binn;
            const u32* xp = &sX[p * 9];
            #pragma unroll
            for (int kk = 0; kk < 9; ++kk) {
                u32 xv = xp[kk];
                xr = fdot2(sWi[kk * NCOL + tid], xv, xr);
                xz = fdot2(sWi[kk * NCOL + NH + tid], xv, xz);
                xn = fdot2(sWi[kk * NCOL + 2 * NH + tid], xv, xn);
            }
        }
        __syncthreads();
        // ---- reduce + gates ----
        if (tid < NH) {
            float sr = sPart[tid] + sPart[NCOL + tid] + sPart[2 * NCOL + tid] + sPart[3 * NCOL + tid];
            float sz = sPart[NH + tid] + sPart[NCOL + NH + tid] + sPart[2 * NCOL + NH + tid] + sPart[3 * NCOL + NH + tid];
            float sn = sPart[2 * NH + tid] + sPart[NCOL + 2 * NH + tid] + sPart[2 * NCOL + 2 * NH + tid] + sPart[3 * NCOL + 2 * NH + tid];
            float r = 1.f / (1.f + __expf(-(sr + xr)));
            float z = 1.f / (1.f + __expf(-(sz + xz)));
            float targ = xn + r * (sn + bnn);
            float e2 = __expf(2.f * targ);
            float n = 1.f - 2.f / (e2 + 1.f);   // tanh, saturates correctly at +-inf
            hreg = (1.f - z) * n + z * hreg;
            _Float16 hh = (_Float16)hreg;
            ((u16*)sH2)[tid] = __builtin_bit_cast(u16, hh);
        }
        __syncthreads();
    }

    // ---------------- MLP tail ----------------
    if (tid < NH) sHf[tid] = hreg;
    __syncthreads();
    if (tid < 128) sHid[tid] = pack2(sHf[2 * tid], sHf[2 * tid + 1]);
    else if (tid < 132) { int i = tid - 128; sHid[tid] = pack2(sMisc[2 * i], sMisc[2 * i + 1]); }
    else if (tid == 132) sHid[132] = pack2(sMisc[8], 0.f);
    __syncthreads();
    // L1: 512 outputs (2 critics x 256)
    {
        int c = tid >> 8, o = tid & 255;
        float acc = b1[c * 256 + o];
        const u32* wp = ws + OFF_W1 + c * 133 * 256 + o;
        #pragma unroll 4
        for (int kk = 0; kk < 133; ++kk) acc = fdot2(wp[kk * 256], sHid[kk], acc);
        acc = fmaxf(acc, 0.f);
        _Float16 a16 = (_Float16)acc;
        sL1[tid] = __builtin_bit_cast(u16, a16);
    }
    __syncthreads();
    // L2
    {
        int c = tid >> 8, o = tid & 255;
        float acc = b2[c * 256 + o];
        const u32* wp = ws + OFF_W2 + c * 128 * 256 + o;
        const u32* hp = (const u32*)sL1 + c * 128;
        #pragma unroll 4
        for (int kk = 0; kk < 128; ++kk) acc = fdot2(wp[kk * 256], hp[kk], acc);
        acc = fmaxf(acc, 0.f);
        _Float16 a16 = (_Float16)acc;
        sL2[tid] = __builtin_bit_cast(u16, a16);
    }
    __syncthreads();
    // L3: 2 outputs via wave reduction
    if (tid < 128) {
        int c = tid >> 6, l = tid & 63;
        const u32* wp = ws + OFF_W3 + c * 128;
        const u32* hp = (const u32*)sL2 + c * 128;
        float acc = fdot2(wp[l], hp[l], 0.f);
        acc = fdot2(wp[64 + l], hp[64 + l], acc);
        #pragma unroll
        for (int off = 32; off > 0; off >>= 1) acc += __shfl_down(acc, off);
        if (l == 0) out[b * 2 + c] = acc + b3[c];
    }
}

extern "C" void kernel_launch(void* const* d_in, const int* in_sizes, int n_in,
                              void* d_out, int out_size, void* d_ws, size_t ws_size,
                              hipStream_t stream) {
    const float* particles = (const float*)d_in[0];
    const float* pweights  = (const float*)d_in[1];
    const float* actions   = (const float*)d_in[2];
    const float* timev     = (const float*)d_in[3];
    const float* Wi        = (const float*)d_in[4];
    const float* bi        = (const float*)d_in[5];
    const float* Whrz      = (const float*)d_in[6];
    const float* Whn       = (const float*)d_in[7];
    const float* bn        = (const float*)d_in[8];
    const float* W1        = (const float*)d_in[9];
    const float* b1        = (const float*)d_in[10];
    const float* W2        = (const float*)d_in[11];
    const float* b2        = (const float*)d_in[12];
    const float* W3        = (const float*)d_in[13];
    const float* b3        = (const float*)d_in[14];
    const int*   nts       = (const int*)d_in[15];
    u32* ws = (u32*)d_ws;
    float* outp = (float*)d_out;

    pack_kernel<<<WS_DWORDS / 256, 256, 0, stream>>>(Wi, Whrz, Whn, W1, W2, W3, ws);
    qnet_kernel<<<NB, 512, 0, stream>>>(particles, pweights, actions, timev,
                                        bi, bn, b1, b2, b3, nts, ws, outp);
}